// Round 5
// baseline (818.523 us; speedup 1.0000x reference)
//
#include <hip/hip_runtime.h>
#include <math.h>

// ws layout (floats):
//   esq   : [4096]
//   state : [64*8192]      f_rest, [b][yx*32+c] (single buffer: apply RMWs via LDS)
//   fhat  : [64*8192]      f_hat accumulator, [b][yx*32+c]
//   z     : [64][256*32]   pooled z rows per scale (v>=V undefined; scan clamps)
//   zsq   : [64][256]
//   psc   : [64][8][256] float   (single slot: scan(s) overwrites after apply(s) read)
//   pix   : [64][8][256] int
#define WS_ESQ   0
#define WS_STATE 4096
#define WS_FHAT  (4096 + 524288)
#define WS_Z     (4096 + 2*524288)
#define WS_ZSQ   (4096 + 3*524288)
#define WS_PSC   (4096 + 3*524288 + 16384)
#define WS_PIX   (4096 + 3*524288 + 16384 + 131072)

__device__ __forceinline__ float4 v4add(float4 a, float4 b) {
    return make_float4(__fadd_rn(a.x,b.x), __fadd_rn(a.y,b.y),
                       __fadd_rn(a.z,b.z), __fadd_rn(a.w,b.w));
}
__device__ __forceinline__ float4 v4sq(float4 a) {
    return make_float4(__fmul_rn(a.x,a.x), __fmul_rn(a.y,a.y),
                       __fmul_rn(a.z,a.z), __fmul_rn(a.w,a.w));
}
// numpy pairwise sum of 32 pre-rounded squares held in 8 float4s
__device__ __forceinline__ float np_pw32(float4 q0, float4 q1, float4 q2, float4 q3,
                                         float4 q4, float4 q5, float4 q6, float4 q7) {
    float4 rA = v4add(v4add(v4add(q0, q2), q4), q6);   // r[0..3]
    float4 rB = v4add(v4add(v4add(q1, q3), q5), q7);   // r[4..7]
    float l = __fadd_rn(__fadd_rn(rA.x, rA.y), __fadd_rn(rA.z, rA.w));
    float h = __fadd_rn(__fadd_rn(rB.x, rB.y), __fadd_rn(rB.z, rB.w));
    return __fadd_rn(l, h);
}

__global__ void vq_prep(const float* __restrict__ emb, float* __restrict__ esq) {
    int j = blockIdx.x * 256 + threadIdx.x;
    if (j < 4096) {
        const float4* e4 = (const float4*)(emb + (size_t)j*32);
        esq[j] = np_pw32(v4sq(e4[0]),v4sq(e4[1]),v4sq(e4[2]),v4sq(e4[3]),
                         v4sq(e4[4]),v4sq(e4[5]),v4sq(e4[6]),v4sq(e4[7]));
    }
}

__device__ __forceinline__ double keys64(double x) {
    // jax keys cubic (a=-0.5)
    if (x < 1.0)      return ((1.5*x - 2.5)*x)*x + 1.0;
    else if (x < 2.0) return ((-0.5*x + 2.5)*x - 4.0)*x + 2.0;
    return 0.0;
}

// One WG per batch: combine prev partial argmins, gather h, bicubic-apply,
// persist state/fhat, pool z for this scale, write z+zsq. All fp32 sequences
// bit-identical to the validated round-3 kernel.
__global__ __launch_bounds__(256) void vq_apply(
    const float* __restrict__ f, const float* __restrict__ emb,
    float* __restrict__ state, float* __restrict__ fhat,
    float* __restrict__ zws, float* __restrict__ zsqws,
    const float* __restrict__ psc, const int* __restrict__ pix,
    int sIdx, int pn, int pnPrev)
{
    __shared__ float frest[256*33];   // [yx*33+c]
    __shared__ float zh[5600];        // union: h [v*32+c] (P3-P5) / pooled z [v*33+c] (P7+)
    __shared__ int   idx_arr[256];
    __shared__ float U[16*16];        // bicubic weights [out][in], fp64->fp32 like jax

    const int tid = threadIdx.x;
    const int b   = blockIdx.x;

    // ---- P1: load f_rest into LDS ----
    if (sIdx == 0) {
        for (int o = tid; o < 8192; o += 256) {            // o = c*256+yx (coalesced in f)
            int c = o >> 8, yx = o & 255;
            frest[yx*33 + c] = f[b*8192 + o];
        }
    } else {
        const float* st = state + (size_t)b*8192;
        for (int o = tid; o < 8192; o += 256)
            frest[(o >> 5)*33 + (o & 31)] = st[o];
    }
    __syncthreads();

    if (sIdx > 0) {
        const int Vp = pnPrev * pnPrev;
        // ---- P2: combine prev-scale partials (ascending chunk = ascending j) ----
        if (tid < Vp) {
            float best = INFINITY; int bi = 0;
            for (int ch = 0; ch < 8; ++ch) {
                float sc = psc[((size_t)b*8 + ch)*256 + tid];
                if (sc < best) { best = sc; bi = pix[((size_t)b*8 + ch)*256 + tid]; }
            }
            idx_arr[tid] = bi;
        }
        __syncthreads();
        // ---- P3: gather h = emb[idx] ----
        for (int t = tid; t < Vp*32; t += 256)
            zh[t] = emb[(size_t)idx_arr[t >> 5]*32 + (t & 31)];
        // ---- P4: bicubic weights in fp64 exactly like jax, cast fp32 after normalize ----
        if (tid < 16) {
            double scl = 16.0 / (double)pnPrev;
            double inv = 1.0 / scl;
            double s = ((double)tid + 0.5) * inv - 0.5;
            double w64[16]; double tot = 0.0;
            for (int q = 0; q < pnPrev; ++q) {
                double wv = keys64(fabs(s - (double)q));
                w64[q] = wv; tot += wv;
            }
            for (int q = 0; q < pnPrev; ++q) U[tid*16 + q] = (float)(w64[q] / tot);
        }
        __syncthreads();
        // ---- P5: upsample-apply, windowed to nonzero taps (bit-identical: zero taps
        //          contribute exact +0.0). term=fl(fl(h*wy)*wx), p outer, q inner. ----
        float* stn = state + (size_t)b*8192;
        float* fh  = fhat + (size_t)b*8192;
        const double inv = 1.0 / (16.0 / (double)pnPrev);
        for (int o = tid; o < 8192; o += 256) {
            int c = o & 31, yx = o >> 5, y = yx >> 4, x = yx & 15;
            double sy = ((double)y + 0.5) * inv - 0.5;
            double sx = ((double)x + 0.5) * inv - 0.5;
            int p0 = (int)floor(sy) - 1, q0 = (int)floor(sx) - 1;
            int pa = max(0, p0), pb = min(pnPrev - 1, p0 + 3);
            int qa = max(0, q0), qb = min(pnPrev - 1, q0 + 3);
            float acc = 0.f;
            for (int p = pa; p <= pb; ++p) {
                float wy = U[y*16 + p];
                for (int q = qa; q <= qb; ++q) {
                    float t0 = __fmul_rn(zh[(p*pnPrev + q)*32 + c], wy);
                    t0 = __fmul_rn(t0, U[x*16 + q]);
                    acc = __fadd_rn(acc, t0);
                }
            }
            float fr = __fsub_rn(frest[yx*33 + c], acc);
            frest[yx*33 + c] = fr;
            stn[o] = fr;
            fh[o] = (sIdx == 1) ? acc : __fadd_rn(fh[o], acc);  // f_hat chain
        }
        __syncthreads();
    } else {
        // s==0: persist permuted f as initial state
        float* stn = state + (size_t)b*8192;
        for (int o = tid; o < 8192; o += 256)
            stn[o] = frest[(o >> 5)*33 + (o & 31)];
    }

    // ---- P7: area pooling -> zh[v*33+c] (np einsum order), skip pn==16 ----
    const int V = pn * pn;
    if (pn < 16) {
        for (int t = tid; t < V*32; t += 256) {
            int v = t >> 5, c = t & 31;
            int p = v / pn, q = v - p*pn;
            int sh = (p*16)/pn, eh = ((p+1)*16 + pn - 1)/pn;
            int sw = (q*16)/pn, ew = ((q+1)*16 + pn - 1)/pn;
            float Mh = (float)(1.0/(double)(eh - sh));
            float Mw = (float)(1.0/(double)(ew - sw));
            float coef = __fmul_rn(Mh, Mw);
            float acc = 0.f;
            for (int hh = sh; hh < eh; ++hh)
                for (int wy = sw; wy < ew; ++wy)
                    acc = __fadd_rn(acc, __fmul_rn(coef, frest[(hh*16 + wy)*33 + c]));
            zh[v*33 + c] = acc;
        }
        __syncthreads();
    }

    // ---- P8: write z rows [v*32+c] + zsq (np pairwise-32) ----
    const float* zsrc = (pn == 16) ? frest : zh;
    for (int t = tid; t < V*32; t += 256)
        zws[(size_t)b*8192 + t] = zsrc[(t >> 5)*33 + (t & 31)];
    if (tid < V) {
        const float* zp = zsrc + tid*33;
        float4 a0 = make_float4(zp[0],zp[1],zp[2],zp[3]);
        float4 a1 = make_float4(zp[4],zp[5],zp[6],zp[7]);
        float4 a2 = make_float4(zp[8],zp[9],zp[10],zp[11]);
        float4 a3 = make_float4(zp[12],zp[13],zp[14],zp[15]);
        float4 a4 = make_float4(zp[16],zp[17],zp[18],zp[19]);
        float4 a5 = make_float4(zp[20],zp[21],zp[22],zp[23]);
        float4 a6 = make_float4(zp[24],zp[25],zp[26],zp[27]);
        float4 a7 = make_float4(zp[28],zp[29],zp[30],zp[31]);
        zsqws[(size_t)b*256 + tid] = np_pw32(v4sq(a0),v4sq(a1),v4sq(a2),v4sq(a3),
                                             v4sq(a4),v4sq(a5),v4sq(a6),v4sq(a7));
    }
}

#define DOT4(E, OFF, Z) \
    acc = __fmaf_rn(E[OFF+0], Z.x, acc); acc = __fmaf_rn(E[OFF+1], Z.y, acc); \
    acc = __fmaf_rn(E[OFF+2], Z.z, acc); acc = __fmaf_rn(E[OFF+3], Z.w, acc);

// 512 WGs = 64 batches x 8 chunks of 512 codes. Lean scan: z -> registers,
// wave-uniform code index => emb rows via s_load. 2 WGs/CU (8 waves/SIMD).
__global__ __launch_bounds__(1024, 8) void vq_scan(
    const float* __restrict__ emb, const float* __restrict__ esq,
    const float* __restrict__ zws, const float* __restrict__ zsqws,
    float* __restrict__ psc, int* __restrict__ pix, int pn)
{
    __shared__ float psc_l[16*64];
    __shared__ int   pix_l[16*64];

    const int tid   = threadIdx.x;
    const int b     = blockIdx.x >> 3;
    const int chunk = blockIdx.x & 7;

    const int V    = pn * pn;
    const int G    = (V + 63) >> 6;
    const int cp   = 16 / G;              // 16(x7 scales), 8, 5, 4
    const int w    = tid >> 6;
    const int lane = tid & 63;
    const int g = w / cp, sub = w - g*cp;

    float4 z0 = {0,0,0,0}, z1 = {0,0,0,0}, z2 = {0,0,0,0}, z3 = {0,0,0,0};
    float4 z4 = {0,0,0,0}, z5 = {0,0,0,0}, z6 = {0,0,0,0}, z7 = {0,0,0,0};
    float myzsq = 0.f;
    if (g < G) {
        const int vc = min(g*64 + lane, V - 1);
        const float4* zp = (const float4*)(zws + ((size_t)b*256 + vc)*32);
        z0 = zp[0]; z1 = zp[1]; z2 = zp[2]; z3 = zp[3];
        z4 = zp[4]; z5 = zp[5]; z6 = zp[6]; z7 = zp[7];
        myzsq = zsqws[(size_t)b*256 + vc];
    }

    // scan 512 codes; d = fl(fl(zsq+esq) - fl(2*g)), g = sequential-k fma (BLAS)
    float best = INFINITY; int bidx = 0;
    if (g < G) {
        const int cszb  = (512 + cp - 1) / cp;
        const int jb    = (chunk << 9) + sub*cszb;
        const int count = min(cszb, 512 - sub*cszb);
        const int jbase = __builtin_amdgcn_readfirstlane(jb);
        const float* __restrict__ ep = emb + (size_t)jbase*32;
        const float* __restrict__ sq = esq + jbase;
        #pragma unroll 2
        for (int jj = 0; jj < count; ++jj) {
            const float* e = ep + jj*32;
            float acc = 0.f;
            DOT4(e, 0,  z0) DOT4(e, 4,  z1) DOT4(e, 8,  z2) DOT4(e, 12, z3)
            DOT4(e, 16, z4) DOT4(e, 20, z5) DOT4(e, 24, z6) DOT4(e, 28, z7)
            float d = __fsub_rn(__fadd_rn(myzsq, sq[jj]), __fmul_rn(2.0f, acc));
            if (d < best) { best = d; bidx = jbase + jj; }   // strict <: first-index ties
        }
    }
    psc_l[w*64 + lane] = best;
    pix_l[w*64 + lane] = bidx;
    __syncthreads();

    // intra-WG reduce (ascending sub => ascending j), write partials
    if (tid < V) {
        int gg = tid >> 6, ll = tid & 63;
        float bb = INFINITY; int bi = 0;
        for (int subi = 0; subi < cp; ++subi) {
            float sc = psc_l[(gg*cp + subi)*64 + ll];
            if (sc < bb) { bb = sc; bi = pix_l[(gg*cp + subi)*64 + ll]; }
        }
        psc[((size_t)b*8 + chunk)*256 + tid] = bb;
        pix[((size_t)b*8 + chunk)*256 + tid] = bi;
    }
}

__global__ __launch_bounds__(1024) void vq_final(
    const float* __restrict__ emb, const float* __restrict__ fhat,
    const float* __restrict__ psc, const int* __restrict__ pix,
    float* __restrict__ out)
{
    __shared__ int idx_arr[256];
    const int tid = threadIdx.x;
    const int b = blockIdx.x;
    if (tid < 256) {
        float best = INFINITY; int bi = 0;
        for (int ch = 0; ch < 8; ++ch) {
            float sc = psc[((size_t)b*8 + ch)*256 + tid];
            if (sc < best) { best = sc; bi = pix[((size_t)b*8 + ch)*256 + tid]; }
        }
        idx_arr[tid] = bi;
    }
    __syncthreads();
    // out = transpose(f_hat + h9), BCHW coalesced; h9 = emb[idx] (last scale: no resize)
    for (int o = tid; o < 8192; o += 1024) {
        int c = o >> 8, yx = o & 255;
        out[b*8192 + o] = __fadd_rn(fhat[(size_t)b*8192 + yx*32 + c],
                                    emb[(size_t)idx_arr[yx]*32 + c]);
    }
}

extern "C" void kernel_launch(void* const* d_in, const int* in_sizes, int n_in,
                              void* d_out, int out_size, void* d_ws, size_t ws_size,
                              hipStream_t stream) {
    const float* f   = (const float*)d_in[0];
    const float* emb = (const float*)d_in[1];
    float* ws  = (float*)d_ws;
    float* out = (float*)d_out;
    float* esq   = ws + WS_ESQ;
    float* state = ws + WS_STATE;
    float* fhatp = ws + WS_FHAT;
    float* zws   = ws + WS_Z;
    float* zsqws = ws + WS_ZSQ;
    float* psc   = ws + WS_PSC;
    int*   pixp  = (int*)(ws + WS_PIX);
    static const int pns[10] = {1, 2, 3, 4, 5, 6, 8, 10, 13, 16};

    vq_prep<<<16, 256, 0, stream>>>(emb, esq);
    for (int s = 0; s < 10; ++s) {
        vq_apply<<<64, 256, 0, stream>>>(f, emb, state, fhatp, zws, zsqws,
                                         psc, pixp, s, pns[s], s > 0 ? pns[s-1] : 0);
        vq_scan<<<512, 1024, 0, stream>>>(emb, esq, zws, zsqws, psc, pixp, pns[s]);
    }
    vq_final<<<64, 1024, 0, stream>>>(emb, fhatp, psc, pixp, out);
}

// Round 6
// 522.959 us; speedup vs baseline: 1.5652x; 1.5652x over previous
//
#include <hip/hip_runtime.h>
#include <math.h>

// ws layout (floats):
//   esq   : [4096]                          @ 0
//   state : [64*8192]  f_rest [b][yx*32+c]  @ 4096
//   fhat  : [64*8192]  [b][yx*32+c]         @ 4096+524288
//   z     : [16384][32] pair=(v*64+b) rows  @ 4096+2*524288
//   psc   : [131072] float (pair*NCB+cb)    @ 4096+3*524288
//   pix   : [131072] int                    @ 4096+3*524288+131072
#define WS_ESQ   0
#define WS_STATE 4096
#define WS_FHAT  (4096 + 524288)
#define WS_Z     (4096 + 2*524288)
#define WS_PSC   (4096 + 3*524288)
#define WS_PIX   (4096 + 3*524288 + 131072)

__device__ __forceinline__ float4 v4add(float4 a, float4 b) {
    return make_float4(__fadd_rn(a.x,b.x), __fadd_rn(a.y,b.y),
                       __fadd_rn(a.z,b.z), __fadd_rn(a.w,b.w));
}
__device__ __forceinline__ float4 v4sq(float4 a) {
    return make_float4(__fmul_rn(a.x,a.x), __fmul_rn(a.y,a.y),
                       __fmul_rn(a.z,a.z), __fmul_rn(a.w,a.w));
}
// numpy pairwise sum of 32 pre-rounded squares held in 8 float4s
__device__ __forceinline__ float np_pw32(float4 q0, float4 q1, float4 q2, float4 q3,
                                         float4 q4, float4 q5, float4 q6, float4 q7) {
    float4 rA = v4add(v4add(v4add(q0, q2), q4), q6);   // r[0..3]
    float4 rB = v4add(v4add(v4add(q1, q3), q5), q7);   // r[4..7]
    float l = __fadd_rn(__fadd_rn(rA.x, rA.y), __fadd_rn(rA.z, rA.w));
    float h = __fadd_rn(__fadd_rn(rB.x, rB.y), __fadd_rn(rB.z, rB.w));
    return __fadd_rn(l, h);
}

__global__ void vq_prep(const float* __restrict__ emb, float* __restrict__ esq) {
    int j = blockIdx.x * 256 + threadIdx.x;
    if (j < 4096) {
        const float4* e4 = (const float4*)(emb + (size_t)j*32);
        esq[j] = np_pw32(v4sq(e4[0]),v4sq(e4[1]),v4sq(e4[2]),v4sq(e4[3]),
                         v4sq(e4[4]),v4sq(e4[5]),v4sq(e4[6]),v4sq(e4[7]));
    }
}

__device__ __forceinline__ double keys64(double x) {
    // jax keys cubic (a=-0.5)
    if (x < 1.0)      return ((1.5*x - 2.5)*x)*x + 1.0;
    else if (x < 2.0) return ((-0.5*x + 2.5)*x - 4.0)*x + 2.0;
    return 0.0;
}

// 256 WGs = 64 batches x 4 channel-groups of 8. Combine prev partial argmins,
// gather h slice, bicubic-apply, persist state/fhat, pool, write z rows.
// All fp32 sequences bit-identical to the validated round-3/4 kernels.
__global__ __launch_bounds__(256) void vq_apply(
    const float* __restrict__ f, const float* __restrict__ emb,
    float* __restrict__ state, float* __restrict__ fhat,
    float* __restrict__ zws,
    const float* __restrict__ psc, const int* __restrict__ pix,
    int sIdx, int pn, int pnPrev, int ncbPrev)
{
    __shared__ float fr[256*9];     // f_rest slice [yx][cc], pad 9
    __shared__ float hs[169*8];     // h slice [v][cc]
    __shared__ int   idx_arr[169];
    __shared__ float U[16*16];      // bicubic weights [out][in], fp64->fp32 like jax

    const int tid = threadIdx.x;
    const int b   = blockIdx.x >> 2;
    const int cg  = blockIdx.x & 3;
    const int c0  = cg * 8;

    // ---- P1: load f_rest slice into LDS ----
    if (sIdx == 0) {
        for (int o = tid; o < 2048; o += 256) {            // f is BCHW: [b][c][yx]
            int cc = o >> 8, yx = o & 255;
            fr[yx*9 + cc] = f[b*8192 + (c0 + cc)*256 + yx];
        }
    } else {
        for (int o = tid; o < 2048; o += 256) {
            int yx = o >> 3, cc = o & 7;
            fr[yx*9 + cc] = state[b*8192 + yx*32 + c0 + cc];
        }
    }
    __syncthreads();

    if (sIdx > 0) {
        const int Vp = pnPrev * pnPrev;
        // ---- P2: combine prev partials over NCB chunks (ascending cb = ascending j) ----
        if (tid < Vp) {
            float best = INFINITY; int bi = 0;
            const size_t pbase = (size_t)((tid << 6) + b) * ncbPrev;  // pair = v*64+b
            for (int ch = 0; ch < ncbPrev; ++ch) {
                float sc = psc[pbase + ch];
                if (sc < best) { best = sc; bi = pix[pbase + ch]; }
            }
            idx_arr[tid] = bi;
        }
        __syncthreads();
        // ---- P3: gather h slice ----
        for (int t = tid; t < Vp*8; t += 256)
            hs[t] = emb[(size_t)idx_arr[t >> 3]*32 + c0 + (t & 7)];
        // ---- P4: bicubic weights in fp64 exactly like jax ----
        if (tid < 16) {
            double scl = 16.0 / (double)pnPrev;
            double inv = 1.0 / scl;
            double s = ((double)tid + 0.5) * inv - 0.5;
            double w64[16]; double tot = 0.0;
            for (int q = 0; q < pnPrev; ++q) {
                double wv = keys64(fabs(s - (double)q));
                w64[q] = wv; tot += wv;
            }
            for (int q = 0; q < pnPrev; ++q) U[tid*16 + q] = (float)(w64[q] / tot);
        }
        __syncthreads();
        // ---- P5: windowed bicubic apply (zero taps = exact +0.0 identities);
        //          term = fl(fl(h*wy)*wx), p outer asc, q inner asc, fl adds ----
        const double inv = 1.0 / (16.0 / (double)pnPrev);
        for (int o = tid; o < 2048; o += 256) {
            int yx = o >> 3, cc = o & 7, y = yx >> 4, x = yx & 15;
            double sy = ((double)y + 0.5) * inv - 0.5;
            double sx = ((double)x + 0.5) * inv - 0.5;
            int p0 = (int)floor(sy) - 1, q0 = (int)floor(sx) - 1;
            int pa = max(0, p0), pb = min(pnPrev - 1, p0 + 3);
            int qa = max(0, q0), qb = min(pnPrev - 1, q0 + 3);
            float acc = 0.f;
            for (int p = pa; p <= pb; ++p) {
                float wy = U[y*16 + p];
                for (int q = qa; q <= qb; ++q) {
                    float t0 = __fmul_rn(hs[(p*pnPrev + q)*8 + cc], wy);
                    t0 = __fmul_rn(t0, U[x*16 + q]);
                    acc = __fadd_rn(acc, t0);
                }
            }
            float frv = __fsub_rn(fr[yx*9 + cc], acc);
            fr[yx*9 + cc] = frv;
            int go = b*8192 + yx*32 + c0 + cc;
            state[go] = frv;
            fhat[go] = (sIdx == 1) ? acc : __fadd_rn(fhat[go], acc);   // f_hat chain
        }
        __syncthreads();
    } else {
        // s==0: persist permuted f as initial state
        for (int o = tid; o < 2048; o += 256) {
            int yx = o >> 3, cc = o & 7;
            state[b*8192 + yx*32 + c0 + cc] = fr[yx*9 + cc];
        }
    }

    // ---- P7: area pool slice (np einsum order: fl(coef*f), h outer, w inner),
    //          write z rows [pair=(v*64+b)][c] ----
    const int V = pn * pn;
    if (pn < 16) {
        for (int t = tid; t < V*8; t += 256) {
            int v = t >> 3, cc = t & 7;
            int p = v / pn, q = v - p*pn;
            int sh = (p*16)/pn, eh = ((p+1)*16 + pn - 1)/pn;
            int sw = (q*16)/pn, ew = ((q+1)*16 + pn - 1)/pn;
            float Mh = (float)(1.0/(double)(eh - sh));
            float Mw = (float)(1.0/(double)(ew - sw));
            float coef = __fmul_rn(Mh, Mw);
            float acc = 0.f;
            for (int hh = sh; hh < eh; ++hh)
                for (int wy = sw; wy < ew; ++wy)
                    acc = __fadd_rn(acc, __fmul_rn(coef, fr[(hh*16 + wy)*9 + cc]));
            zws[((size_t)(v << 6) + b)*32 + c0 + cc] = acc;
        }
    } else {
        for (int o = tid; o < 2048; o += 256) {
            int yx = o >> 3, cc = o & 7;
            zws[((size_t)(yx << 6) + b)*32 + c0 + cc] = fr[yx*9 + cc];
        }
    }
}

#define DOT4P(E, OFF, ZA, ZB) \
    acc0 = __fmaf_rn(E[OFF+0], ZA.x, acc0); acc1 = __fmaf_rn(E[OFF+0], ZB.x, acc1); \
    acc0 = __fmaf_rn(E[OFF+1], ZA.y, acc0); acc1 = __fmaf_rn(E[OFF+1], ZB.y, acc1); \
    acc0 = __fmaf_rn(E[OFF+2], ZA.z, acc0); acc1 = __fmaf_rn(E[OFF+2], ZB.z, acc1); \
    acc0 = __fmaf_rn(E[OFF+3], ZA.w, acc0); acc1 = __fmaf_rn(E[OFF+3], ZB.w, acc1);

// Batch-packed scan: lane = (b,v) pair, 2 pairs per lane (zero lane waste).
// Grid = pairblocks(128 pairs) x NCB code-chunks. Wave scans CB/4 codes;
// emb row is wave-uniform -> scalar loads broadcast against z registers.
__global__ __launch_bounds__(256, 4) void vq_scan(
    const float* __restrict__ emb, const float* __restrict__ esq,
    const float* __restrict__ zws, float* __restrict__ psc, int* __restrict__ pix,
    int V, int ncbMask, int ncbShift, int CB)
{
    __shared__ float psc_l[512];
    __shared__ int   pix_l[512];

    const int tid  = threadIdx.x;
    const int cb   = blockIdx.x & ncbMask;
    const int pblk = blockIdx.x >> ncbShift;
    const int w    = __builtin_amdgcn_readfirstlane(tid >> 6);
    const int lane = tid & 63;
    const int N = V << 6;

    const int pair0 = (pblk << 7) + lane;
    const int pair1 = pair0 + 64;
    const int p0c = min(pair0, N - 1), p1c = min(pair1, N - 1);

    const float4* za = (const float4*)(zws + (size_t)p0c*32);
    const float4* zb = (const float4*)(zws + (size_t)p1c*32);
    float4 a0 = za[0], a1 = za[1], a2 = za[2], a3 = za[3];
    float4 a4 = za[4], a5 = za[5], a6 = za[6], a7 = za[7];
    float4 b0 = zb[0], b1 = zb[1], b2 = zb[2], b3 = zb[3];
    float4 b4 = zb[4], b5 = zb[5], b6 = zb[6], b7 = zb[7];
    float zsq0 = np_pw32(v4sq(a0),v4sq(a1),v4sq(a2),v4sq(a3),
                         v4sq(a4),v4sq(a5),v4sq(a6),v4sq(a7));
    float zsq1 = np_pw32(v4sq(b0),v4sq(b1),v4sq(b2),v4sq(b3),
                         v4sq(b4),v4sq(b5),v4sq(b6),v4sq(b7));

    const int wc    = CB >> 2;                 // codes per wave
    const int jbase = __builtin_amdgcn_readfirstlane(cb*CB + w*wc);
    const float* __restrict__ ep = emb + (size_t)jbase*32;
    const float* __restrict__ sq = esq + jbase;

    // d = fl(fl(zsq+esq) - fl(2*g)), g = sequential-k fma (BLAS order)
    float best0 = INFINITY, best1 = INFINITY; int bi0 = 0, bi1 = 0;
    #pragma unroll 2
    for (int jj = 0; jj < wc; ++jj) {
        const float* e = ep + jj*32;
        float acc0 = 0.f, acc1 = 0.f;
        DOT4P(e, 0,  a0, b0) DOT4P(e, 4,  a1, b1) DOT4P(e, 8,  a2, b2) DOT4P(e, 12, a3, b3)
        DOT4P(e, 16, a4, b4) DOT4P(e, 20, a5, b5) DOT4P(e, 24, a6, b6) DOT4P(e, 28, a7, b7)
        float sqj = sq[jj];
        float d0 = __fsub_rn(__fadd_rn(zsq0, sqj), __fmul_rn(2.0f, acc0));
        float d1 = __fsub_rn(__fadd_rn(zsq1, sqj), __fmul_rn(2.0f, acc1));
        int j = jbase + jj;
        if (d0 < best0) { best0 = d0; bi0 = j; }   // strict <: first-index ties
        if (d1 < best1) { best1 = d1; bi1 = j; }
    }
    psc_l[w*128 + lane]      = best0;  pix_l[w*128 + lane]      = bi0;
    psc_l[w*128 + 64 + lane] = best1;  pix_l[w*128 + 64 + lane] = bi1;
    __syncthreads();

    // reduce across 4 waves (ascending w = ascending j), write partials
    if (tid < 128) {
        int p = (pblk << 7) + tid;
        if (p < N) {
            float bb = INFINITY; int bi = 0;
            #pragma unroll
            for (int ww = 0; ww < 4; ++ww) {
                float sc = psc_l[ww*128 + tid];
                if (sc < bb) { bb = sc; bi = pix_l[ww*128 + tid]; }
            }
            psc[(size_t)p*(ncbMask + 1) + cb] = bb;
            pix[(size_t)p*(ncbMask + 1) + cb] = bi;
        }
    }
}

__global__ __launch_bounds__(256) void vq_final(
    const float* __restrict__ emb, const float* __restrict__ fhat,
    const float* __restrict__ psc, const int* __restrict__ pix,
    float* __restrict__ out)
{
    __shared__ int idx_arr[256];
    const int tid = threadIdx.x;
    const int b = blockIdx.x;
    {   // combine last scale (pn=16, NCB=8) partials; pair = yx*64 + b
        float best = INFINITY; int bi = 0;
        const size_t pbase = (size_t)((tid << 6) + b) * 8;
        for (int ch = 0; ch < 8; ++ch) {
            float sc = psc[pbase + ch];
            if (sc < best) { best = sc; bi = pix[pbase + ch]; }
        }
        idx_arr[tid] = bi;
    }
    __syncthreads();
    // out = transpose(f_hat + h9), BCHW coalesced (last scale: no resize)
    for (int o = tid; o < 8192; o += 256) {
        int c = o >> 8, yx = o & 255;
        out[b*8192 + o] = __fadd_rn(fhat[(size_t)b*8192 + yx*32 + c],
                                    emb[(size_t)idx_arr[yx]*32 + c]);
    }
}

extern "C" void kernel_launch(void* const* d_in, const int* in_sizes, int n_in,
                              void* d_out, int out_size, void* d_ws, size_t ws_size,
                              hipStream_t stream) {
    const float* f   = (const float*)d_in[0];
    const float* emb = (const float*)d_in[1];
    float* ws  = (float*)d_ws;
    float* out = (float*)d_out;
    float* esq   = ws + WS_ESQ;
    float* state = ws + WS_STATE;
    float* fhatp = ws + WS_FHAT;
    float* zws   = ws + WS_Z;
    float* psc   = ws + WS_PSC;
    int*   pixp  = (int*)(ws + WS_PIX);
    static const int pns[10]  = {1, 2, 3, 4, 5, 6, 8, 10, 13, 16};
    static const int ncbl[10] = {7, 7, 6, 6, 5, 5, 4, 4, 3, 3};   // log2(NCB)

    vq_prep<<<16, 256, 0, stream>>>(emb, esq);
    for (int s = 0; s < 10; ++s) {
        int pn = pns[s], V = pn*pn, sh = ncbl[s];
        int PB = (V + 1) >> 1;                 // pairblocks of 128 (b,v) pairs
        vq_apply<<<256, 256, 0, stream>>>(f, emb, state, fhatp, zws, psc, pixp,
                                          s, pn, s > 0 ? pns[s-1] : 0,
                                          s > 0 ? (1 << ncbl[s-1]) : 0);
        vq_scan<<<PB << sh, 256, 0, stream>>>(emb, esq, zws, psc, pixp,
                                              V, (1 << sh) - 1, sh, 4096 >> sh);
    }
    vq_final<<<64, 256, 0, stream>>>(emb, fhatp, psc, pixp, out);
}